// Round 1
// baseline (207.940 us; speedup 1.0000x reference)
//
#include <hip/hip_runtime.h>
#include <hip/hip_bf16.h>

typedef short bf16x8 __attribute__((ext_vector_type(8)));
typedef float f32x4  __attribute__((ext_vector_type(4)));

#define C_IN   256
#define C_OUT  256
#define HWDIM  56
#define HWHW   (56*56)      // 3136
#define BH     2            // output rows per block
#define NROW   4            // BH + 2 halo rows
#define NCOL   58           // 56 + 2 halo cols
#define NJJ    (NROW*NCOL)  // 232 spatial slots in LDS tile
#define ROWSH  40           // shorts per jj row: 32 ch + 8 pad = 80 B (bank-spread stride)
#define CHUNK  32           // channels per K chunk
#define NCHUNK 8

__device__ __forceinline__ unsigned short f2bf(float f) {
    unsigned int u = __float_as_uint(f);
    u += 0x7fffu + ((u >> 16) & 1u);   // RNE
    return (unsigned short)(u >> 16);
}

// prepass: W[o][c*9+t] fp32 -> Wt[t][o][c] bf16
__global__ void wprep(const float* __restrict__ w, unsigned short* __restrict__ wt) {
    int idx = blockIdx.x * blockDim.x + threadIdx.x;   // 0 .. 589823
    int t   = idx >> 16;
    int rem = idx & 65535;
    int o   = rem >> 8;
    int c   = rem & 255;
    wt[idx] = f2bf(w[o * 2304 + c * 9 + t]);
}

__global__ __launch_bounds__(512, 2)
void conv_kernel(const float* __restrict__ x, const unsigned short* __restrict__ wt,
                 const float* __restrict__ bias, float* __restrict__ out) {
    __shared__ short xs[2][NJJ * ROWSH];   // 2 x 18560 B

    const int hb = blockIdx.x;    // 0..27
    const int n  = blockIdx.y;    // 0..31
    const int h0 = hb * BH;

    const int tid  = threadIdx.x;
    const int lane = tid & 63;
    const int wv   = tid >> 6;    // wave 0..7 -> 32 output channels each
    const int g    = lane >> 4;   // k-group 0..3
    const int lcol = lane & 15;

    // B-frag base LDS offsets (shorts) for the 7 N-frags (tap shift added as const)
    int bbase[7];
#pragma unroll
    for (int f = 0; f < 7; ++f) {
        int j = f * 16 + lcol;            // 0..111 within 2x56 tile
        bbase[f] = ((j / 56) * NCOL + (j % 56)) * ROWSH + 8 * g;
    }

    // staging mapping: lanes -> consecutive jj (coalesced global reads)
    const int scw  = tid >> 5;    // channel-pair 0..15
    const int sjj0 = tid & 31;    // jj base, step 32

    const float* xn = x + (size_t)n * C_IN * HWHW;

    float sv0[8], sv1[8];

    f32x4 acc[2][7];
#pragma unroll
    for (int m = 0; m < 2; ++m)
#pragma unroll
        for (int f = 0; f < 7; ++f) acc[m][f] = (f32x4){0.f, 0.f, 0.f, 0.f};

    // A-frag base: wt[(t*256 + o)*256 + c], o = wv*32 + m*16 + lcol, c = c8*32 + 8g
    const unsigned short* wrow = wt + (size_t)(wv * 32 + lcol) * 256 + 8 * g;

    auto stage_load = [&](int c8) {
        const float* xc0 = xn + (size_t)(c8 * CHUNK + 2 * scw) * HWHW;
        const float* xc1 = xc0 + HWHW;
#pragma unroll
        for (int it = 0; it < 8; ++it) {
            int jj = sjj0 + 32 * it;
            int r = jj / 58, wc = jj % 58;
            int hh = h0 - 1 + r, ww = wc - 1;
            bool ok = (jj < NJJ) & (hh >= 0) & (hh < 56) & (ww >= 0) & (ww < 56);
            int off = hh * 56 + ww;
            sv0[it] = ok ? xc0[off] : 0.0f;
            sv1[it] = ok ? xc1[off] : 0.0f;
        }
    };
    auto stage_write = [&](int buf) {
#pragma unroll
        for (int it = 0; it < 8; ++it) {
            int jj = sjj0 + 32 * it;
            if (jj < NJJ) {
                unsigned int p = (unsigned int)f2bf(sv0[it]) |
                                 ((unsigned int)f2bf(sv1[it]) << 16);
                *(unsigned int*)&xs[buf][jj * ROWSH + 2 * scw] = p;
            }
        }
    };

    stage_load(0);
    stage_write(0);
    __syncthreads();

    for (int c8 = 0; c8 < NCHUNK; ++c8) {
        if (c8 < NCHUNK - 1) stage_load(c8 + 1);   // issue early; hide under MFMA
        const short* xb = &xs[c8 & 1][0];
        const int cofs = c8 * CHUNK;
#pragma unroll
        for (int t = 0; t < 9; ++t) {
            const int kh = t / 3, kw = t % 3;
            const int dt = (kh * NCOL + kw) * ROWSH;   // const per unrolled tap
            bf16x8 a0 = *(const bf16x8*)(wrow + t * 65536 + cofs);
            bf16x8 a1 = *(const bf16x8*)(wrow + t * 65536 + 4096 + cofs);
#pragma unroll
            for (int f = 0; f < 7; ++f) {
                bf16x8 b = *(const bf16x8*)&xb[bbase[f] + dt];
                acc[0][f] = __builtin_amdgcn_mfma_f32_16x16x32_bf16(a0, b, acc[0][f], 0, 0, 0);
                acc[1][f] = __builtin_amdgcn_mfma_f32_16x16x32_bf16(a1, b, acc[1][f], 0, 0, 0);
            }
        }
        __syncthreads();
        if (c8 < NCHUNK - 1) stage_write((c8 + 1) & 1);
        __syncthreads();
    }

    // epilogue: D layout col=lane&15, row=4*(lane>>4)+q
    float* yb = out + (size_t)n * C_OUT * HWHW + h0 * 56;
#pragma unroll
    for (int m = 0; m < 2; ++m) {
#pragma unroll
        for (int q = 0; q < 4; ++q) {
            int o = wv * 32 + m * 16 + 4 * g + q;
            float bs = bias[o];
            float* yo = yb + (size_t)o * HWHW;
#pragma unroll
            for (int f = 0; f < 7; ++f) {
                int j = f * 16 + lcol;         // contiguous across the 2 rows
                yo[j] = acc[m][f][q] + bs;
            }
        }
    }
}

extern "C" void kernel_launch(void* const* d_in, const int* in_sizes, int n_in,
                              void* d_out, int out_size, void* d_ws, size_t ws_size,
                              hipStream_t stream) {
    const float* x    = (const float*)d_in[0];
    const float* w    = (const float*)d_in[1];
    const float* bias = (const float*)d_in[2];
    float* out        = (float*)d_out;
    unsigned short* wt = (unsigned short*)d_ws;   // 9*256*256*2 = 1.18 MB

    wprep<<<2304, 256, 0, stream>>>(w, wt);
    dim3 grid(28, 32);   // (h-blocks, n)
    conv_kernel<<<grid, 512, 0, stream>>>(x, wt, bias, out);
}

// Round 2
// 128.168 us; speedup vs baseline: 1.6224x; 1.6224x over previous
//
#include <hip/hip_runtime.h>
#include <hip/hip_bf16.h>

typedef short bf16x8 __attribute__((ext_vector_type(8)));
typedef float f32x4  __attribute__((ext_vector_type(4)));

#define HWHW   3136
#define BH     4            // output rows per block
#define NROW   6            // BH + 2 halo
#define NCOL   58
#define NJJ    (NROW*NCOL)  // 348
#define ROWSH  40           // shorts per jj row (80 B: bank-uniform for b128)
#define CHUNK  32
#define NCHUNK 8

__device__ __forceinline__ unsigned short f2bf(float f) {
    unsigned int u = __float_as_uint(f);
    u += 0x7fffu + ((u >> 16) & 1u);   // RNE
    return (unsigned short)(u >> 16);
}

// prepass: W[o][c*9+t] fp32 -> lane-ordered bf16 fragments:
// wt[ (((t*8 + c8)*16 + om)*64 + lane)*8 + e ] = W[om*16 + (lane&15)][c8*32 + (lane>>4)*8 + e]
__global__ void wprep(const float* __restrict__ w, unsigned short* __restrict__ wt) {
    int idx = blockIdx.x * blockDim.x + threadIdx.x;   // 0 .. 589823
    int e    = idx & 7;
    int lane = (idx >> 3) & 63;
    int om   = (idx >> 9) & 15;
    int c8   = (idx >> 13) & 7;
    int t    = idx >> 16;                              // 0..8
    int o = om * 16 + (lane & 15);
    int c = c8 * 32 + (lane >> 4) * 8 + e;
    wt[idx] = f2bf(w[o * 2304 + c * 9 + t]);
}

__global__ __launch_bounds__(512, 2)
void conv_kernel(const float* __restrict__ x, const unsigned short* __restrict__ wt,
                 const float* __restrict__ bias, float* __restrict__ out) {
    __shared__ short xs[2][NJJ * ROWSH];   // 2 x 27840 B

    const int hb = blockIdx.x;    // 0..13
    const int n  = blockIdx.y;    // 0..31
    const int h0 = hb * BH;

    const int tid  = threadIdx.x;
    const int lane = tid & 63;
    const int wv   = tid >> 6;    // 0..7
    const int wm   = wv & 3;      // M group: out-ch base 64*wm
    const int ng   = wv >> 2;     // N group: col base 112*ng
    const int g    = lane >> 4;
    const int lcol = lane & 15;

    // B-frag base LDS offsets (shorts), tap shift added as compile-time const
    int bbase[7];
#pragma unroll
    for (int f = 0; f < 7; ++f) {
        int j = ng * 112 + f * 16 + lcol;        // 0..223
        bbase[f] = ((j / 56) * NCOL + (j % 56)) * ROWSH + 8 * g;
    }

    // staging mapping
    const int cpair = tid >> 5;   // 0..15 -> channels 2cp, 2cp+1
    const int col0  = tid & 31;

    const float* xn = x + (size_t)n * 256 * HWHW;

    float sv0[6][2], sv1[6][2];

    f32x4 acc[4][7];
#pragma unroll
    for (int m = 0; m < 4; ++m)
#pragma unroll
        for (int f = 0; f < 7; ++f) acc[m][f] = (f32x4){0.f, 0.f, 0.f, 0.f};

    const unsigned short* wl = wt + (size_t)lane * 8;

    auto stage_load = [&](int c8) {
        const float* xc0 = xn + (size_t)(c8 * CHUNK + 2 * cpair) * HWHW;
        const float* xc1 = xc0 + HWHW;
#pragma unroll
        for (int r = 0; r < 6; ++r) {
            int hh = h0 - 1 + r;
            bool rok = (hh >= 0) & (hh < 56);
#pragma unroll
            for (int ci = 0; ci < 2; ++ci) {
                int col = col0 + 32 * ci;
                int ww  = col - 1;
                bool ok = rok & (col < 58) & (ww >= 0) & (ww < 56);
                int off = hh * 56 + ww;
                sv0[r][ci] = ok ? xc0[off] : 0.0f;
                sv1[r][ci] = ok ? xc1[off] : 0.0f;
            }
        }
    };
    auto stage_write = [&](int buf) {
#pragma unroll
        for (int r = 0; r < 6; ++r)
#pragma unroll
            for (int ci = 0; ci < 2; ++ci) {
                int col = col0 + 32 * ci;
                if (col < 58) {
                    unsigned int p = (unsigned int)f2bf(sv0[r][ci]) |
                                     ((unsigned int)f2bf(sv1[r][ci]) << 16);
                    *(unsigned int*)&xs[buf][(r * NCOL + col) * ROWSH + 2 * cpair] = p;
                }
            }
    };

    stage_load(0);
    stage_write(0);
    __syncthreads();

    for (int c8 = 0; c8 < NCHUNK; ++c8) {
        if (c8 < NCHUNK - 1) stage_load(c8 + 1);   // issue early; hide under MFMA
        const short* xb = &xs[c8 & 1][0];

        // A double-buffer across taps (all indices compile-time under unroll)
        bf16x8 a0[4], a1[4];
#pragma unroll
        for (int m = 0; m < 4; ++m)
            a0[m] = *(const bf16x8*)(wl + (size_t)(((0 * 8 + c8) * 16) + 4 * wm + m) * 512);

#pragma unroll
        for (int t = 0; t < 9; ++t) {
            bf16x8* ac = (t & 1) ? a1 : a0;
            bf16x8* an = (t & 1) ? a0 : a1;
            if (t < 8) {
#pragma unroll
                for (int m = 0; m < 4; ++m)
                    an[m] = *(const bf16x8*)(wl + (size_t)((((t + 1) * 8 + c8) * 16) + 4 * wm + m) * 512);
            }
            const int dt = ((t / 3) * NCOL + (t % 3)) * ROWSH;
#pragma unroll
            for (int f = 0; f < 7; ++f) {
                bf16x8 b = *(const bf16x8*)&xb[bbase[f] + dt];
#pragma unroll
                for (int m = 0; m < 4; ++m)
                    acc[m][f] = __builtin_amdgcn_mfma_f32_16x16x32_bf16(ac[m], b, acc[m][f], 0, 0, 0);
            }
        }

        if (c8 < NCHUNK - 1) stage_write((c8 + 1) & 1);
        __syncthreads();
    }

    // epilogue: D layout col=lane&15 (spatial), row=4g+q (out-ch within 16)
#pragma unroll
    for (int m = 0; m < 4; ++m) {
#pragma unroll
        for (int q = 0; q < 4; ++q) {
            int o = 64 * wm + 16 * m + 4 * g + q;
            float bs = bias[o];
            float* yo = out + ((size_t)n * 256 + o) * HWHW + h0 * 56;
#pragma unroll
            for (int f = 0; f < 7; ++f) {
                int j = ng * 112 + f * 16 + lcol;
                yo[j] = acc[m][f][q] + bs;
            }
        }
    }
}

extern "C" void kernel_launch(void* const* d_in, const int* in_sizes, int n_in,
                              void* d_out, int out_size, void* d_ws, size_t ws_size,
                              hipStream_t stream) {
    const float* x    = (const float*)d_in[0];
    const float* w    = (const float*)d_in[1];
    const float* bias = (const float*)d_in[2];
    float* out        = (float*)d_out;
    unsigned short* wt = (unsigned short*)d_ws;   // 589824 shorts = 1.18 MB

    wprep<<<2304, 256, 0, stream>>>(w, wt);
    dim3 grid(14, 32);   // (h-blocks, n)
    conv_kernel<<<grid, 512, 0, stream>>>(x, wt, bias, out);
}